// Round 1
// baseline (529.969 us; speedup 1.0000x reference)
//
#include <hip/hip_runtime.h>
#include <hip/hip_bf16.h>

#define N_POS 4096
#define C_IN 64
#define IC 32

// ---------------- Stage A: 1x1 conv projections g/theta/phi ----------------
__global__ __launch_bounds__(256) void proj_kernel(
    const float* __restrict__ x,
    const float* __restrict__ g_w, const float* __restrict__ g_b,
    const float* __restrict__ th_w, const float* __restrict__ th_b,
    const float* __restrict__ ph_w, const float* __restrict__ ph_b,
    float* __restrict__ gx, float* __restrict__ thx, float* __restrict__ phx)
{
    __shared__ float w[96][64];
    __shared__ float bias[96];
    int tid = threadIdx.x;
    for (int i = tid; i < 2048; i += 256) {
        int o = i >> 6, c = i & 63;
        w[o][c]      = g_w[i];
        w[32 + o][c] = th_w[i];
        w[64 + o][c] = ph_w[i];
    }
    if (tid < 32) { bias[tid] = g_b[tid]; bias[32 + tid] = th_b[tid]; bias[64 + tid] = ph_b[tid]; }
    __syncthreads();

    int ng = blockIdx.x * 256 + tid;   // 0..32767  (8 batches * 4096 positions)
    int b = ng >> 12, n = ng & 4095;
    const float* xb = x + (size_t)b * C_IN * N_POS + n;
    float xr[64];
    #pragma unroll
    for (int c = 0; c < 64; c++) xr[c] = xb[(size_t)c * N_POS];

    for (int o = 0; o < 96; o++) {
        float acc = bias[o];
        const float4* w4 = (const float4*)w[o];
        #pragma unroll
        for (int c4 = 0; c4 < 16; c4++) {
            float4 wv = w4[c4];
            acc += wv.x * xr[c4*4+0] + wv.y * xr[c4*4+1]
                 + wv.z * xr[c4*4+2] + wv.w * xr[c4*4+3];
        }
        float* dst = (o < 32) ? gx : (o < 64) ? thx : phx;
        int oc = o & 31;
        dst[((size_t)b * IC + oc) * N_POS + n] = acc;
    }
}

// ------------- Stage B: non-local attention, fused streaming softmax --------
// block = 256 threads: 32 q-groups (2 queries each) x 8 m-groups (8 m each)
// grid  = 8 batches * 64 query-tiles (64 queries per block)
__global__ __launch_bounds__(256) void attn_kernel(
    const float* __restrict__ thx, const float* __restrict__ phx,
    const float* __restrict__ gx, float* __restrict__ y)
{
    __shared__ float sphi[32][64];
    __shared__ float sg[32][64];
    int tid = threadIdx.x;
    int b  = blockIdx.x >> 6;
    int q0 = (blockIdx.x & 63) << 6;
    int qg = tid >> 3, mg = tid & 7;

    const float* thb = thx + (size_t)b * IC * N_POS;
    const float* phb = phx + (size_t)b * IC * N_POS;
    const float* gb_ = gx  + (size_t)b * IC * N_POS;

    // stage theta tile [32c][64q] through LDS, pull this thread's 2 queries to regs
    for (int i = tid; i < 2048; i += 256)
        sphi[i >> 6][i & 63] = thb[(size_t)(i >> 6) * N_POS + q0 + (i & 63)];
    __syncthreads();
    float th[2][32];
    #pragma unroll
    for (int qs = 0; qs < 2; qs++)
        #pragma unroll
        for (int c = 0; c < 32; c++)
            th[qs][c] = sphi[c][qg * 2 + qs];
    __syncthreads();

    float yacc[2][32];
    #pragma unroll
    for (int qs = 0; qs < 2; qs++)
        #pragma unroll
        for (int c = 0; c < 32; c++) yacc[qs][c] = 0.f;
    float sume[2] = {0.f, 0.f};

    for (int m0 = 0; m0 < N_POS; m0 += 64) {
        for (int i = tid; i < 2048; i += 256) {
            int c = i >> 6, j = i & 63;
            sphi[c][j] = phb[(size_t)c * N_POS + m0 + j];
            sg[c][j]   = gb_[(size_t)c * N_POS + m0 + j];
        }
        __syncthreads();

        float s[2][8];
        #pragma unroll
        for (int qs = 0; qs < 2; qs++)
            #pragma unroll
            for (int j = 0; j < 8; j++) s[qs][j] = 0.f;

        #pragma unroll
        for (int c = 0; c < 32; c++) {
            float pv[8];
            *(float4*)&pv[0] = ((const float4*)sphi[c])[mg * 2];
            *(float4*)&pv[4] = ((const float4*)sphi[c])[mg * 2 + 1];
            #pragma unroll
            for (int j = 0; j < 8; j++) {
                s[0][j] += th[0][c] * pv[j];
                s[1][j] += th[1][c] * pv[j];
            }
        }

        // unscaled softmax numerator: logits statistically bounded (|s| < ~40),
        // exp without max-shift is safe in fp32 and identical after normalize
        float p[2][8];
        #pragma unroll
        for (int qs = 0; qs < 2; qs++)
            #pragma unroll
            for (int j = 0; j < 8; j++) {
                p[qs][j] = __expf(s[qs][j]);
                sume[qs] += p[qs][j];
            }

        #pragma unroll
        for (int c = 0; c < 32; c++) {
            float gv[8];
            *(float4*)&gv[0] = ((const float4*)sg[c])[mg * 2];
            *(float4*)&gv[4] = ((const float4*)sg[c])[mg * 2 + 1];
            #pragma unroll
            for (int j = 0; j < 8; j++) {
                yacc[0][c] += p[0][j] * gv[j];
                yacc[1][c] += p[1][j] * gv[j];
            }
        }
        __syncthreads();
    }

    // reduce the 8 m-groups (lanes differing in bits 0..2) + normalize
    #pragma unroll
    for (int qs = 0; qs < 2; qs++) {
        #pragma unroll
        for (int d = 1; d < 8; d <<= 1) sume[qs] += __shfl_xor(sume[qs], d);
        #pragma unroll
        for (int c = 0; c < 32; c++) {
            float v = yacc[qs][c];
            #pragma unroll
            for (int d = 1; d < 8; d <<= 1) v += __shfl_xor(v, d);
            yacc[qs][c] = v;
        }
    }
    if (mg == 0) {
        #pragma unroll
        for (int qs = 0; qs < 2; qs++) {
            float inv = 1.f / sume[qs];
            int q = q0 + qg * 2 + qs;
            #pragma unroll
            for (int c = 0; c < 32; c++)
                y[((size_t)b * IC + c) * N_POS + q] = yacc[qs][c] * inv;
        }
    }
}

// ------------- Stage C: memory-bank cross attention (256 keys) --------------
__global__ __launch_bounds__(256) void mbattn_kernel(
    const float* __restrict__ phx, const float* __restrict__ mb,
    float* __restrict__ y1)
{
    __shared__ float smb[32][256];
    int tid = threadIdx.x;
    for (int i = tid; i < 8192; i += 256) smb[i >> 8][i & 255] = mb[i];
    __syncthreads();

    int ng = blockIdx.x * 256 + tid;
    int b = ng >> 12, n = ng & 4095;
    float ph[32];
    #pragma unroll
    for (int c = 0; c < 32; c++) ph[c] = phx[((size_t)b * IC + c) * N_POS + n];

    float ya[32];
    #pragma unroll
    for (int c = 0; c < 32; c++) ya[c] = 0.f;
    float se = 0.f;
    const float scale = 0.17677669529663687f;  // 32^-0.5

    for (int k0 = 0; k0 < 256; k0 += 8) {
        float s[8];
        #pragma unroll
        for (int j = 0; j < 8; j++) s[j] = 0.f;
        #pragma unroll
        for (int c = 0; c < 32; c++) {
            float mv[8];
            *(float4*)&mv[0] = *(const float4*)&smb[c][k0];
            *(float4*)&mv[4] = *(const float4*)&smb[c][k0 + 4];
            #pragma unroll
            for (int j = 0; j < 8; j++) s[j] += ph[c] * mv[j];
        }
        float p[8];
        #pragma unroll
        for (int j = 0; j < 8; j++) { p[j] = __expf(s[j] * scale); se += p[j]; }
        #pragma unroll
        for (int c = 0; c < 32; c++) {
            float mv[8];
            *(float4*)&mv[0] = *(const float4*)&smb[c][k0];
            *(float4*)&mv[4] = *(const float4*)&smb[c][k0 + 4];
            #pragma unroll
            for (int j = 0; j < 8; j++) ya[c] += p[j] * mv[j];
        }
    }
    float inv = 1.f / se;
    #pragma unroll
    for (int c = 0; c < 32; c++)
        y1[((size_t)b * IC + c) * N_POS + n] = ya[c] * inv;
}

// ------------- Stage D: W(y) + x + Wz1(y1) ----------------------------------
__global__ __launch_bounds__(256) void out_kernel(
    const float* __restrict__ x,
    const float* __restrict__ Ww, const float* __restrict__ Wb,
    const float* __restrict__ Wzw, const float* __restrict__ Wzb,
    const float* __restrict__ y, const float* __restrict__ y1,
    float* __restrict__ out)
{
    __shared__ float sW[64][32], sWz[64][32];
    __shared__ float sb[64], sbz[64];
    int tid = threadIdx.x;
    for (int i = tid; i < 2048; i += 256) { sW[i >> 5][i & 31] = Ww[i]; sWz[i >> 5][i & 31] = Wzw[i]; }
    if (tid < 64) { sb[tid] = Wb[tid]; sbz[tid] = Wzb[tid]; }
    __syncthreads();

    int ng = blockIdx.x * 256 + tid;
    int b = ng >> 12, n = ng & 4095;
    float yv[32], y1v[32];
    #pragma unroll
    for (int c = 0; c < 32; c++) {
        yv[c]  = y [((size_t)b * IC + c) * N_POS + n];
        y1v[c] = y1[((size_t)b * IC + c) * N_POS + n];
    }
    const float* xb = x   + (size_t)b * C_IN * N_POS + n;
    float*       ob = out + (size_t)b * C_IN * N_POS + n;
    for (int o = 0; o < 64; o++) {
        float acc = sb[o] + sbz[o] + xb[(size_t)o * N_POS];
        const float4* w4  = (const float4*)sW[o];
        const float4* wz4 = (const float4*)sWz[o];
        #pragma unroll
        for (int c4 = 0; c4 < 8; c4++) {
            float4 a = w4[c4], z = wz4[c4];
            acc += a.x * yv[c4*4+0] + a.y * yv[c4*4+1] + a.z * yv[c4*4+2] + a.w * yv[c4*4+3];
            acc += z.x * y1v[c4*4+0] + z.y * y1v[c4*4+1] + z.z * y1v[c4*4+2] + z.w * y1v[c4*4+3];
        }
        ob[(size_t)o * N_POS] = acc;
    }
}

extern "C" void kernel_launch(void* const* d_in, const int* in_sizes, int n_in,
                              void* d_out, int out_size, void* d_ws, size_t ws_size,
                              hipStream_t stream) {
    const float* x    = (const float*)d_in[0];
    const float* g_w  = (const float*)d_in[1];
    const float* g_b  = (const float*)d_in[2];
    const float* th_w = (const float*)d_in[3];
    const float* th_b = (const float*)d_in[4];
    const float* ph_w = (const float*)d_in[5];
    const float* ph_b = (const float*)d_in[6];
    const float* W_w  = (const float*)d_in[7];
    const float* W_b  = (const float*)d_in[8];
    const float* Wz_w = (const float*)d_in[9];
    const float* Wz_b = (const float*)d_in[10];
    const float* mb   = (const float*)d_in[11];
    float* out = (float*)d_out;

    const size_t PLANE = (size_t)8 * IC * N_POS;  // 1M floats = 4MB
    float* gx  = (float*)d_ws;
    float* thx = gx  + PLANE;
    float* phx = thx + PLANE;
    float* yy  = phx + PLANE;
    float* y1  = yy  + PLANE;

    proj_kernel<<<128, 256, 0, stream>>>(x, g_w, g_b, th_w, th_b, ph_w, ph_b, gx, thx, phx);
    attn_kernel<<<512, 256, 0, stream>>>(thx, phx, gx, yy);
    mbattn_kernel<<<128, 256, 0, stream>>>(phx, mb, y1);
    out_kernel<<<128, 256, 0, stream>>>(x, W_w, W_b, Wz_w, Wz_b, yy, y1, out);
}

// Round 2
// 107.139 us; speedup vs baseline: 4.9466x; 4.9466x over previous
//
#include <hip/hip_runtime.h>
#include <hip/hip_bf16.h>

#define N_POS 4096
#define C_IN 64
#define IC 32

typedef float f32x16 __attribute__((ext_vector_type(16)));
typedef short bf16x8 __attribute__((ext_vector_type(8)));
typedef unsigned int uint;
typedef uint uint4v __attribute__((ext_vector_type(4)));

static __device__ __forceinline__ unsigned short f2bf(float f) {
    __hip_bfloat16 h = __float2bfloat16(f);
    return __builtin_bit_cast(unsigned short, h);
}
static __device__ __forceinline__ float bf2f(unsigned short u) {
    unsigned int v = ((unsigned int)u) << 16;
    return __builtin_bit_cast(float, v);
}
static __device__ __forceinline__ uint packbf2(float lo, float hi) {
    return (uint)f2bf(lo) | ((uint)f2bf(hi) << 16);
}

// ---------------- Stage A: projections -> bf16 MFMA layouts ----------------
// blockIdx.y: 0 = g (layout [b][c][n]), 1 = theta ([b][n][c]), 2 = phi ([b][n][c])
__global__ __launch_bounds__(256) void proj_kernel(
    const float* __restrict__ x,
    const float* __restrict__ g_w, const float* __restrict__ g_b,
    const float* __restrict__ th_w, const float* __restrict__ th_b,
    const float* __restrict__ ph_w, const float* __restrict__ ph_b,
    unsigned short* __restrict__ gcn, unsigned short* __restrict__ tht,
    unsigned short* __restrict__ pht)
{
    int pj = blockIdx.y;
    const float* wsrc = (pj == 0) ? g_w : (pj == 1) ? th_w : ph_w;
    const float* bsrc = (pj == 0) ? g_b : (pj == 1) ? th_b : ph_b;
    __shared__ float w[32][64];
    __shared__ float bias[32];
    int tid = threadIdx.x;
    for (int i = tid; i < 2048; i += 256) w[i >> 6][i & 63] = wsrc[i];
    if (tid < 32) bias[tid] = bsrc[tid];
    __syncthreads();

    int ng = blockIdx.x * 256 + tid;
    int b = ng >> 12, n = ng & 4095;
    const float* xb = x + (size_t)b * C_IN * N_POS + n;
    float xr[64];
    #pragma unroll
    for (int c = 0; c < 64; c++) xr[c] = xb[(size_t)c * N_POS];

    float acc[32];
    #pragma unroll
    for (int o = 0; o < 32; o++) {
        float a = bias[o];
        const float4* w4 = (const float4*)w[o];
        #pragma unroll
        for (int c4 = 0; c4 < 16; c4++) {
            float4 wv = w4[c4];
            a += wv.x * xr[c4*4+0] + wv.y * xr[c4*4+1]
               + wv.z * xr[c4*4+2] + wv.w * xr[c4*4+3];
        }
        acc[o] = a;
    }

    if (pj == 0) {
        #pragma unroll
        for (int c = 0; c < 32; c++)
            gcn[((size_t)(b * IC + c)) * N_POS + n] = f2bf(acc[c]);
    } else {
        unsigned short* dst = ((pj == 1) ? tht : pht) + ((size_t)(b * N_POS + n)) * IC;
        uint4v pk[2];
        #pragma unroll
        for (int i = 0; i < 8; i++) {
            uint v = packbf2(acc[2*i], acc[2*i+1]);
            pk[i >> 2][i & 3] = v;
        }
        *(uint4v*)dst = pk[0];
        *(uint4v*)(dst + 8) = pk[1];
        uint4v pk2[2];
        #pragma unroll
        for (int i = 0; i < 8; i++) {
            uint v = packbf2(acc[16 + 2*i], acc[16 + 2*i+1]);
            pk2[i >> 2][i & 3] = v;
        }
        *(uint4v*)(dst + 16) = pk2[0];
        *(uint4v*)(dst + 24) = pk2[1];
    }
}

// -------- mb prep: fp32 (32x256) -> bf16 mbb [c][k] and mbt [k][c] ----------
__global__ __launch_bounds__(256) void mbprep_kernel(
    const float* __restrict__ mb, unsigned short* __restrict__ mbt,
    unsigned short* __restrict__ mbb)
{
    int i = blockIdx.x * 256 + threadIdx.x;   // 8192
    int c = i >> 8, k = i & 255;
    unsigned short u = f2bf(mb[i]);
    mbb[i] = u;
    mbt[k * 32 + c] = u;
}

// ------------- Stage B: non-local attention via 32x32x16 bf16 MFMA ----------
// One wave = one 32-query tile x one m-half (2048 keys). 512 blocks x 4 waves.
// Writes UNNORMALIZED partial (yacc, sum_exp); out_kernel normalizes.
__global__ __launch_bounds__(256) void attn_kernel(
    const unsigned short* __restrict__ tht, const unsigned short* __restrict__ pht,
    const unsigned short* __restrict__ gcn, float* __restrict__ yp,
    float* __restrict__ dnm)
{
    int tid = threadIdx.x;
    int widx = tid >> 6, lane = tid & 63;
    int bid = blockIdx.x;
    int b = bid & 7;                       // batch -> XCD locality
    int lw = (bid >> 3) * 4 + widx;        // 0..255 within batch
    int qt = lw >> 1, s = lw & 1;
    int q0 = qt * 32, mbase = s * 2048;
    int cl = lane & 31, h = lane >> 5;

    // theta B-fragments (hoisted): theta^T rows q0+cl, cols 8h..8h+7 (+16)
    const unsigned short* thp = tht + ((size_t)(b * N_POS + q0 + cl)) * IC + 8 * h;
    bf16x8 thf0 = *(const bf16x8*)thp;
    bf16x8 thf1 = *(const bf16x8*)(thp + 16);

    const unsigned short* phbase = pht + (size_t)b * N_POS * IC;
    const unsigned short* gbase  = gcn + ((size_t)(b * IC + cl)) * N_POS;

    f32x16 yacc, zero;
    #pragma unroll
    for (int i = 0; i < 16; i++) { yacc[i] = 0.f; zero[i] = 0.f; }
    float sume = 0.f;

    #pragma unroll 2
    for (int mt = 0; mt < 64; ++mt) {
        int m0 = mbase + mt * 32;
        const unsigned short* php = phbase + ((size_t)(m0 + cl)) * IC + 8 * h;
        bf16x8 phf0 = *(const bf16x8*)php;
        bf16x8 phf1 = *(const bf16x8*)(php + 16);
        const unsigned short* gp = gbase + m0 + 8 * h;
        bf16x8 gf0 = *(const bf16x8*)gp;
        bf16x8 gf1 = *(const bf16x8*)(gp + 16);

        // S^T[m][q] over K=32 channels: two chained MFMAs
        f32x16 sv = __builtin_amdgcn_mfma_f32_32x32x16_bf16(phf0, thf0, zero, 0, 0, 0);
        sv = __builtin_amdgcn_mfma_f32_32x32x16_bf16(phf1, thf1, sv, 0, 0, 0);

        // exp (no max shift: logits bounded), accumulate denominator, pack bf16
        uint w[8];
        #pragma unroll
        for (int i = 0; i < 8; i++) {
            float p0 = __expf(sv[2*i]);
            float p1 = __expf(sv[2*i+1]);
            sume += p0 + p1;
            w[i] = packbf2(p0, p1);
        }
        uint wsw[8];
        #pragma unroll
        for (int i = 0; i < 8; i++) wsw[i] = (uint)__shfl_xor((int)w[i], 32);

        // PV A-fragments: P[q=lane&31][m = 8h+j] built from own + swapped words
        uint4v a0, a1;
        a0[0] = h ? wsw[2] : w[0];  a0[1] = h ? wsw[3] : w[1];
        a0[2] = h ? w[2] : wsw[0];  a0[3] = h ? w[3] : wsw[1];
        a1[0] = h ? wsw[6] : w[4];  a1[1] = h ? wsw[7] : w[5];
        a1[2] = h ? w[6] : wsw[4];  a1[3] = h ? w[7] : wsw[5];

        yacc = __builtin_amdgcn_mfma_f32_32x32x16_bf16(
            __builtin_bit_cast(bf16x8, a0), gf0, yacc, 0, 0, 0);
        yacc = __builtin_amdgcn_mfma_f32_32x32x16_bf16(
            __builtin_bit_cast(bf16x8, a1), gf1, yacc, 0, 0, 0);
    }

    // write partials: tile = (b,qt,s); denom per q col (both halves hold full sum)
    sume += __shfl_xor(sume, 32);
    size_t tile = ((size_t)(b * 128 + qt)) * 2 + s;
    if (lane < 32) dnm[tile * 32 + cl] = sume;
    float* ypt = yp + tile * 1024;
    #pragma unroll
    for (int r = 0; r < 16; r++) {
        int q = (r & 3) + 8 * (r >> 2) + 4 * h;
        ypt[q * 32 + cl] = yacc[r];
    }
}

// ------------- Stage C: memory-bank attention via MFMA ----------------------
__global__ __launch_bounds__(256) void mb_attn_kernel(
    const unsigned short* __restrict__ pht, const unsigned short* __restrict__ mbt,
    const unsigned short* __restrict__ mbb, unsigned short* __restrict__ y1)
{
    int tid = threadIdx.x;
    int widx = tid >> 6, lane = tid & 63;
    int gwid = blockIdx.x * 4 + widx;      // 0..1023
    int b = gwid >> 7, qt = gwid & 127;
    int q0 = qt * 32;
    int cl = lane & 31, h = lane >> 5;

    const unsigned short* php = pht + ((size_t)(b * N_POS + q0 + cl)) * IC + 8 * h;
    bf16x8 qf0 = *(const bf16x8*)php;
    bf16x8 qf1 = *(const bf16x8*)(php + 16);

    f32x16 yacc, zero;
    #pragma unroll
    for (int i = 0; i < 16; i++) { yacc[i] = 0.f; zero[i] = 0.f; }
    float sume = 0.f;
    const float scale = 0.17677669529663687f;  // 32^-0.5

    #pragma unroll 2
    for (int kt = 0; kt < 8; ++kt) {
        int k0 = kt * 32;
        const unsigned short* ap = mbt + ((size_t)(k0 + cl)) * IC + 8 * h;
        bf16x8 af0 = *(const bf16x8*)ap;
        bf16x8 af1 = *(const bf16x8*)(ap + 16);
        const unsigned short* bp = mbb + (size_t)cl * 256 + k0 + 8 * h;
        bf16x8 bf0 = *(const bf16x8*)bp;
        bf16x8 bf1 = *(const bf16x8*)(bp + 16);

        f32x16 sv = __builtin_amdgcn_mfma_f32_32x32x16_bf16(af0, qf0, zero, 0, 0, 0);
        sv = __builtin_amdgcn_mfma_f32_32x32x16_bf16(af1, qf1, sv, 0, 0, 0);

        uint w[8];
        #pragma unroll
        for (int i = 0; i < 8; i++) {
            float p0 = __expf(sv[2*i] * scale);
            float p1 = __expf(sv[2*i+1] * scale);
            sume += p0 + p1;
            w[i] = packbf2(p0, p1);
        }
        uint wsw[8];
        #pragma unroll
        for (int i = 0; i < 8; i++) wsw[i] = (uint)__shfl_xor((int)w[i], 32);

        uint4v a0, a1;
        a0[0] = h ? wsw[2] : w[0];  a0[1] = h ? wsw[3] : w[1];
        a0[2] = h ? w[2] : wsw[0];  a0[3] = h ? w[3] : wsw[1];
        a1[0] = h ? wsw[6] : w[4];  a1[1] = h ? wsw[7] : w[5];
        a1[2] = h ? w[6] : wsw[4];  a1[3] = h ? w[7] : wsw[5];

        yacc = __builtin_amdgcn_mfma_f32_32x32x16_bf16(
            __builtin_bit_cast(bf16x8, a0), bf0, yacc, 0, 0, 0);
        yacc = __builtin_amdgcn_mfma_f32_32x32x16_bf16(
            __builtin_bit_cast(bf16x8, a1), bf1, yacc, 0, 0, 0);
    }

    sume += __shfl_xor(sume, 32);          // full denom, per q = lane&31
    unsigned short* y1b = y1 + (size_t)(b * IC + cl) * N_POS + q0;
    #pragma unroll
    for (int r = 0; r < 16; r++) {
        int q = (r & 3) + 8 * (r >> 2) + 4 * h;
        float d = __shfl(sume, q);
        y1b[q] = f2bf(yacc[r] / d);
    }
}

// ------------- Stage D: normalize + W(y) + x + Wz1(y1) ----------------------
// blockIdx.y in {0,1} selects 32-output half.
__global__ __launch_bounds__(256) void out_kernel(
    const float* __restrict__ x,
    const float* __restrict__ Ww, const float* __restrict__ Wb,
    const float* __restrict__ Wzw, const float* __restrict__ Wzb,
    const float* __restrict__ yp, const float* __restrict__ dnm,
    const unsigned short* __restrict__ y1, float* __restrict__ out)
{
    int oh = blockIdx.y;
    __shared__ float sW[32][32], sWz[32][32];
    __shared__ float sb[32], sbz[32];
    int tid = threadIdx.x;
    for (int i = tid; i < 1024; i += 256) {
        int o = i >> 5, c = i & 31;
        sW[o][c]  = Ww[(oh * 32 + o) * 32 + c];
        sWz[o][c] = Wzw[(oh * 32 + o) * 32 + c];
    }
    if (tid < 32) { sb[tid] = Wb[oh * 32 + tid]; sbz[tid] = Wzb[oh * 32 + tid]; }
    __syncthreads();

    int ng = blockIdx.x * 256 + tid;
    int b = ng >> 12, n = ng & 4095;
    int qt = n >> 5, q = n & 31;
    size_t t0 = ((size_t)(b * 128 + qt)) * 2;
    float inv = 1.f / (dnm[t0 * 32 + q] + dnm[t0 * 32 + 32 + q]);

    const float* yp0 = yp + t0 * 1024 + q * 32;
    const float* yp1 = yp0 + 1024;
    float yv[32], y1v[32];
    #pragma unroll
    for (int c4 = 0; c4 < 8; c4++) {
        float4 v0 = ((const float4*)yp0)[c4];
        float4 v1 = ((const float4*)yp1)[c4];
        yv[c4*4+0] = (v0.x + v1.x) * inv;
        yv[c4*4+1] = (v0.y + v1.y) * inv;
        yv[c4*4+2] = (v0.z + v1.z) * inv;
        yv[c4*4+3] = (v0.w + v1.w) * inv;
    }
    const unsigned short* y1p = y1 + (size_t)b * IC * N_POS + n;
    #pragma unroll
    for (int c = 0; c < 32; c++) y1v[c] = bf2f(y1p[(size_t)c * N_POS]);

    const float* xb = x   + (size_t)(b * C_IN + oh * 32) * N_POS + n;
    float*       ob = out + (size_t)(b * C_IN + oh * 32) * N_POS + n;
    for (int o = 0; o < 32; o++) {
        float acc = sb[o] + sbz[o] + xb[(size_t)o * N_POS];
        const float4* w4  = (const float4*)sW[o];
        const float4* wz4 = (const float4*)sWz[o];
        #pragma unroll
        for (int c4 = 0; c4 < 8; c4++) {
            float4 a = w4[c4], z = wz4[c4];
            acc += a.x * yv[c4*4+0] + a.y * yv[c4*4+1] + a.z * yv[c4*4+2] + a.w * yv[c4*4+3];
            acc += z.x * y1v[c4*4+0] + z.y * y1v[c4*4+1] + z.z * y1v[c4*4+2] + z.w * y1v[c4*4+3];
        }
        ob[(size_t)o * N_POS] = acc;
    }
}

extern "C" void kernel_launch(void* const* d_in, const int* in_sizes, int n_in,
                              void* d_out, int out_size, void* d_ws, size_t ws_size,
                              hipStream_t stream) {
    const float* x    = (const float*)d_in[0];
    const float* g_w  = (const float*)d_in[1];
    const float* g_b  = (const float*)d_in[2];
    const float* th_w = (const float*)d_in[3];
    const float* th_b = (const float*)d_in[4];
    const float* ph_w = (const float*)d_in[5];
    const float* ph_b = (const float*)d_in[6];
    const float* W_w  = (const float*)d_in[7];
    const float* W_b  = (const float*)d_in[8];
    const float* Wz_w = (const float*)d_in[9];
    const float* Wz_b = (const float*)d_in[10];
    const float* mb   = (const float*)d_in[11];
    float* out = (float*)d_out;

    char* w = (char*)d_ws;
    unsigned short* tht = (unsigned short*)w;                    // 2 MB
    unsigned short* pht = (unsigned short*)(w + (2u << 20));     // 2 MB
    unsigned short* gcn = (unsigned short*)(w + (4u << 20));     // 2 MB
    unsigned short* mbt = (unsigned short*)(w + (6u << 20));     // 16 KB
    unsigned short* mbb = (unsigned short*)(w + (6u << 20) + 16384);
    float* yp  = (float*)(w + (7u << 20));                       // 8 MB
    float* dnm = (float*)(w + (15u << 20));                      // 256 KB
    unsigned short* y1 = (unsigned short*)(w + (16u << 20));     // 2 MB

    proj_kernel<<<dim3(128, 3), 256, 0, stream>>>(x, g_w, g_b, th_w, th_b,
                                                  ph_w, ph_b, gcn, tht, pht);
    mbprep_kernel<<<32, 256, 0, stream>>>(mb, mbt, mbb);
    attn_kernel<<<512, 256, 0, stream>>>(tht, pht, gcn, yp, dnm);
    mb_attn_kernel<<<256, 256, 0, stream>>>(pht, mbt, mbb, y1);
    out_kernel<<<dim3(128, 2), 256, 0, stream>>>(x, W_w, W_b, Wz_w, Wz_b,
                                                 yp, dnm, y1, out);
}